// Round 5
// baseline (736.493 us; speedup 1.0000x reference)
//
#include <hip/hip_runtime.h>

#define BS 256

using half4 = __attribute__((ext_vector_type(4))) _Float16;

template<typename T>
__device__ __forceinline__ float4 load4(const T* p) {
    if constexpr (sizeof(T) == 4) {
        return *(const float4*)p;
    } else {
        half4 v = *(const half4*)p;
        return make_float4((float)v.x, (float)v.y, (float)v.z, (float)v.w);
    }
}
template<typename T>
__device__ __forceinline__ void store4(T* p, float4 v) {
    if constexpr (sizeof(T) == 4) {
        *(float4*)p = v;
    } else {
        half4 h = {(_Float16)v.x, (_Float16)v.y, (_Float16)v.z, (_Float16)v.w};
        *(half4*)p = h;
    }
}

// ---------------- CSR build ----------------

__global__ __launch_bounds__(BS) void k_zero2(int* a, int* b, int n) {
    int i = blockIdx.x * BS + threadIdx.x;
    if (i < n) { a[i] = 0; b[i] = 0; }
}

// XCD-sliced histogram: block handles slice (blockIdx.x & 7); atomics stay
// within a 50KB cnt range -> one XCD's L2 (block->XCD round-robin heuristic;
// correctness does not depend on the mapping).
__global__ __launch_bounds__(BS) void k_hist(const int* __restrict__ dst, int* __restrict__ cnt,
                                             int E, int N) {
    int slice = blockIdx.x & 7;
    int chunk = blockIdx.x >> 3;
    int lo = (int)((long long)N * slice / 8);
    int hi = (int)((long long)N * (slice + 1) / 8);
    int e0 = chunk * (BS * 4) + threadIdx.x;
    #pragma unroll
    for (int j = 0; j < 4; ++j) {
        int e = e0 + j * BS;
        if (e < E) {
            int d = dst[e];
            if (d >= lo && d < hi) atomicAdd(&cnt[d], 1);
        }
    }
}

__global__ __launch_bounds__(BS) void k_dinv(const int* __restrict__ cnt, float* __restrict__ dinv, int N) {
    int i = blockIdx.x * BS + threadIdx.x;
    if (i < N) dinv[i] = rsqrtf((float)(cnt[i] + 1));   // +1 = self-loop
}

__global__ __launch_bounds__(BS) void k_scan1(const int* __restrict__ cnt, int* __restrict__ bsum, int N) {
    __shared__ int s[BS];
    int i = blockIdx.x * BS + threadIdx.x;
    s[threadIdx.x] = (i < N) ? cnt[i] : 0;
    __syncthreads();
    for (int off = BS / 2; off > 0; off >>= 1) {
        if (threadIdx.x < off) s[threadIdx.x] += s[threadIdx.x + off];
        __syncthreads();
    }
    if (threadIdx.x == 0) bsum[blockIdx.x] = s[0];
}

__global__ __launch_bounds__(512) void k_scan2(int* bsum, int nb) {
    __shared__ int s[512];
    int t = threadIdx.x;
    int v = (t < nb) ? bsum[t] : 0;
    s[t] = v;
    __syncthreads();
    for (int off = 1; off < 512; off <<= 1) {
        int u = (t >= off) ? s[t - off] : 0;
        __syncthreads();
        s[t] += u;
        __syncthreads();
    }
    if (t < nb) bsum[t] = s[t] - v;   // exclusive of self
}

__global__ __launch_bounds__(BS) void k_scan3(const int* __restrict__ cnt, const int* __restrict__ boff,
                                              int* __restrict__ row_ptr, int N) {
    __shared__ int s[BS];
    int t = threadIdx.x;
    int i = blockIdx.x * BS + t;
    int v = (i < N) ? cnt[i] : 0;
    s[t] = v;
    __syncthreads();
    for (int off = 1; off < BS; off <<= 1) {
        int u = (t >= off) ? s[t - off] : 0;
        __syncthreads();
        s[t] += u;
        __syncthreads();
    }
    int base = boff[blockIdx.x];
    if (i < N) row_ptr[i] = base + s[t] - v;
    if (i == N - 1) row_ptr[N] = base + s[t];
}

// XCD-sliced CSR fill: block (slice s, chunk c) scans chunk's edges, writes
// only those with dst in slice s. Entry region per slice = E/8*8B = 1.6MB ->
// fits one XCD L2, killing the 8x scattered-write amplification.
__global__ __launch_bounds__(BS) void k_fill(const int* __restrict__ src, const int* __restrict__ dst,
                                             const int* __restrict__ row_ptr, int* __restrict__ fillpos,
                                             const float* __restrict__ dinv, uint2* __restrict__ entries,
                                             int E, int N) {
    int slice = blockIdx.x & 7;
    int chunk = blockIdx.x >> 3;
    int lo = (int)((long long)N * slice / 8);
    int hi = (int)((long long)N * (slice + 1) / 8);
    int e0 = chunk * (BS * 4) + threadIdx.x;
    #pragma unroll
    for (int j = 0; j < 4; ++j) {
        int e = e0 + j * BS;
        if (e < E) {
            int d = dst[e];
            if (d >= lo && d < hi) {
                int s = src[e];
                int pos = row_ptr[d] + atomicAdd(&fillpos[d], 1);
                float w = dinv[s] * dinv[d];
                entries[pos] = make_uint2((unsigned)s, __float_as_uint(w));
            }
        }
    }
}

// ---------------- dense transform ----------------
// out[N, LDOUT(pad0)] = H[N, LDIN] @ W[K, M] (+bias)(+relu); W via scalar loads.
// blockIdx.y column-split: block computes cols [y*CH, y*CH+CH) clamped.
template<int K, int M, int CH, int LDIN, int LDOUT, bool BIAS, bool RELU, typename TOUT>
__global__ __launch_bounds__(BS) void k_gemm(const float* __restrict__ H, const float* __restrict__ Wg,
                                             const float* __restrict__ bias, TOUT* __restrict__ out, int N) {
    int row = blockIdx.x * BS + threadIdx.x;
    bool ok = row < N;
    int rr = ok ? row : (N - 1);            // clamp: safe loads, masked stores
    const float* hp = H + (size_t)rr * LDIN;
    int c0 = blockIdx.y * CH;

    float acc[CH];
    #pragma unroll
    for (int m = 0; m < CH; ++m) acc[m] = 0.f;

    constexpr int K4 = K & ~3;
    #pragma unroll 2
    for (int k = 0; k < K4; k += 4) {
        float4 hv = *(const float4*)(hp + k);
        float h[4] = {hv.x, hv.y, hv.z, hv.w};
        #pragma unroll
        for (int j = 0; j < 4; ++j) {
            const float* wrow = Wg + (size_t)(k + j) * M;
            #pragma unroll
            for (int m = 0; m < CH; ++m) {
                int c = c0 + m; if (c > M - 1) c = M - 1;   // uniform, k-invariant
                acc[m] = fmaf(h[j], wrow[c], acc[m]);
            }
        }
    }
    #pragma unroll
    for (int k = K4; k < K; ++k) {
        float h = hp[k];
        const float* wrow = Wg + (size_t)k * M;
        #pragma unroll
        for (int m = 0; m < CH; ++m) {
            int c = c0 + m; if (c > M - 1) c = M - 1;
            acc[m] = fmaf(h, wrow[c], acc[m]);
        }
    }

    if (!ok) return;
    TOUT* op = out + (size_t)row * LDOUT;
    #pragma unroll
    for (int g = 0; g < CH / 4; ++g) {
        int cb = c0 + 4 * g;
        if (cb >= LDOUT) break;
        float4 v;
        float* vp = &v.x;
        #pragma unroll
        for (int j = 0; j < 4; ++j) {
            int c = cb + j;
            float x = (c < M) ? acc[4 * g + j] : 0.f;
            if (BIAS && c < M) x += bias[c];
            if (RELU) x = fmaxf(x, 0.f);
            vp[j] = x;
        }
        store4(op + cb, v);
    }
}

// ---------------- normalized aggregation ----------------
// out[i,:] = dinv_i^2*T[i,:] + sum_e w_e * T[src_e,:]  (+bias)(+relu)
template<typename TIN, typename TOUT, int M, int M4, bool BIAS, bool RELU>
__global__ __launch_bounds__(BS) void k_agg(const TIN* __restrict__ T, TOUT* __restrict__ out,
                                            const int* __restrict__ row_ptr, const uint2* __restrict__ entries,
                                            const float* __restrict__ dinv, const float* __restrict__ bias,
                                            int N) {
    constexpr int CG = M4 / 4;
    int idx = blockIdx.x * BS + threadIdx.x;
    if (idx >= N * CG) return;
    int i  = idx / CG;                // const divisor -> magic mul
    int cg = idx - i * CG;
    int c0 = cg * 4;

    float di = dinv[i];
    float4 t0 = load4(T + (size_t)i * M4 + c0);
    float w0 = di * di;
    float4 acc0 = make_float4(w0 * t0.x, w0 * t0.y, w0 * t0.z, w0 * t0.w);
    float4 acc1 = make_float4(0.f, 0.f, 0.f, 0.f);

    int e0 = row_ptr[i], e1 = row_ptr[i + 1];
    int e = e0;
    for (; e + 3 < e1; e += 4) {
        uint2 ea = entries[e];
        uint2 eb = entries[e + 1];
        uint2 ec = entries[e + 2];
        uint2 ed = entries[e + 3];
        float4 ta = load4(T + (size_t)ea.x * M4 + c0);
        float4 tb = load4(T + (size_t)eb.x * M4 + c0);
        float4 tc = load4(T + (size_t)ec.x * M4 + c0);
        float4 td = load4(T + (size_t)ed.x * M4 + c0);
        float wa = __uint_as_float(ea.y), wb = __uint_as_float(eb.y);
        float wc = __uint_as_float(ec.y), wd = __uint_as_float(ed.y);
        acc0.x = fmaf(wa, ta.x, acc0.x); acc0.y = fmaf(wa, ta.y, acc0.y);
        acc0.z = fmaf(wa, ta.z, acc0.z); acc0.w = fmaf(wa, ta.w, acc0.w);
        acc1.x = fmaf(wb, tb.x, acc1.x); acc1.y = fmaf(wb, tb.y, acc1.y);
        acc1.z = fmaf(wb, tb.z, acc1.z); acc1.w = fmaf(wb, tb.w, acc1.w);
        acc0.x = fmaf(wc, tc.x, acc0.x); acc0.y = fmaf(wc, tc.y, acc0.y);
        acc0.z = fmaf(wc, tc.z, acc0.z); acc0.w = fmaf(wc, tc.w, acc0.w);
        acc1.x = fmaf(wd, td.x, acc1.x); acc1.y = fmaf(wd, td.y, acc1.y);
        acc1.z = fmaf(wd, td.z, acc1.z); acc1.w = fmaf(wd, td.w, acc1.w);
    }
    for (; e < e1; ++e) {
        uint2 ea = entries[e];
        float4 ta = load4(T + (size_t)ea.x * M4 + c0);
        float wa = __uint_as_float(ea.y);
        acc0.x = fmaf(wa, ta.x, acc0.x); acc0.y = fmaf(wa, ta.y, acc0.y);
        acc0.z = fmaf(wa, ta.z, acc0.z); acc0.w = fmaf(wa, ta.w, acc0.w);
    }
    acc0.x += acc1.x; acc0.y += acc1.y; acc0.z += acc1.z; acc0.w += acc1.w;

    float* vp = &acc0.x;
    #pragma unroll
    for (int j = 0; j < 4; ++j) {
        if (BIAS && (c0 + j) < M) vp[j] += bias[c0 + j];
        if (RELU) vp[j] = fmaxf(vp[j], 0.f);
    }
    store4(out + (size_t)i * M4 + c0, acc0);
}

// ---------------- driver ----------------

extern "C" void kernel_launch(void* const* d_in, const int* in_sizes, int n_in,
                              void* d_out, int out_size, void* d_ws, size_t ws_size,
                              hipStream_t stream) {
    const float* x  = (const float*)d_in[0];
    const float* W1 = (const float*)d_in[1];
    const float* b1 = (const float*)d_in[2];
    const float* W2 = (const float*)d_in[3];
    const float* b2 = (const float*)d_in[4];
    const float* W3 = (const float*)d_in[5];
    const float* b3 = (const float*)d_in[6];
    const float* W4 = (const float*)d_in[7];
    const float* b4 = (const float*)d_in[8];
    const int* edge_index = (const int*)d_in[9];

    const int N = in_sizes[0] / 88;
    const int E = in_sizes[9] / 2;
    const int* src = edge_index;
    const int* dst = edge_index + E;

    char* p = (char*)d_ws;
    auto carve = [&](size_t bytes) { void* r = p; p += (bytes + 255) & ~(size_t)255; return r; };
    int*   cnt     = (int*)  carve((size_t)N * 4);
    float* dinv    = (float*)carve((size_t)N * 4);
    int*   row_ptr = (int*)  carve((size_t)(N + 1) * 4);
    int*   fillpos = (int*)  carve((size_t)N * 4);
    int*   bsum    = (int*)  carve(4096);
    uint2* entries = (uint2*)carve((size_t)E * 8);
    _Float16* hA   = (_Float16*)carve((size_t)N * 68 * 2);
    _Float16* hB   = (_Float16*)carve((size_t)N * 68 * 2);
    float*    fA   = (float*)   carve((size_t)N * 68 * 4);

    int gN = (N + BS - 1) / BS;
    int chunks = (E + BS * 4 - 1) / (BS * 4);

    k_zero2<<<gN, BS, 0, stream>>>(cnt, fillpos, N);
    k_hist <<<chunks * 8, BS, 0, stream>>>(dst, cnt, E, N);
    k_dinv <<<gN, BS, 0, stream>>>(cnt, dinv, N);
    int nb = gN;
    k_scan1<<<nb, BS, 0, stream>>>(cnt, bsum, N);
    k_scan2<<<1, 512, 0, stream>>>(bsum, nb);
    k_scan3<<<nb, BS, 0, stream>>>(cnt, bsum, row_ptr, N);
    k_fill <<<chunks * 8, BS, 0, stream>>>(src, dst, row_ptr, fillpos, dinv, entries, E, N);

    dim3 ggrid(gN, 4);
    auto agg_grid = [&](int CG) { return (N * CG + BS - 1) / BS; };

    // G1: x(f32,88) @ W1 -> hA(half,68)   [CH=20, y=4]
    k_gemm<88, 65, 20, 88, 68, false, false, _Float16><<<ggrid, BS, 0, stream>>>(x, W1, nullptr, hA, N);
    // A1: agg(hA) +b1 +relu -> fA(f32,68)
    k_agg<_Float16, float, 65, 68, true, true><<<agg_grid(17), BS, 0, stream>>>(hA, fA, row_ptr, entries, dinv, b1, N);
    // G2: fA(68) @ W2 -> hB(half,52)      [CH=16, y=4]
    k_gemm<65, 50, 16, 68, 52, false, false, _Float16><<<ggrid, BS, 0, stream>>>(fA, W2, nullptr, hB, N);
    // A2: agg(hB) +b2 -> hA(half,52)
    k_agg<_Float16, _Float16, 50, 52, true, false><<<agg_grid(13), BS, 0, stream>>>(hB, hA, row_ptr, entries, dinv, b2, N);
    // A3: agg(hA) -> fA(f32,52)
    k_agg<_Float16, float, 50, 52, false, false><<<agg_grid(13), BS, 0, stream>>>(hA, fA, row_ptr, entries, dinv, nullptr, N);
    // G3: fA(52) @ W3 +b3 +relu -> hB(half,68)  [CH=20, y=4]
    k_gemm<50, 65, 20, 52, 68, true, true, _Float16><<<ggrid, BS, 0, stream>>>(fA, W3, b3, hB, N);
    // A4: agg(hB) -> fA(f32,68)
    k_agg<_Float16, float, 65, 68, false, false><<<agg_grid(17), BS, 0, stream>>>(hB, fA, row_ptr, entries, dinv, nullptr, N);
    // G4: fA(68) @ W4 +b4 -> d_out(f32,88)  [CH=24, y=4]
    k_gemm<65, 88, 24, 68, 88, true, false, float><<<ggrid, BS, 0, stream>>>(fA, W4, b4, (float*)d_out, N);
}

// Round 6
// 604.139 us; speedup vs baseline: 1.2191x; 1.2191x over previous
//
#include <hip/hip_runtime.h>

#define BS 256

using half4 = __attribute__((ext_vector_type(4))) _Float16;

template<typename T>
__device__ __forceinline__ float4 load4(const T* p) {
    if constexpr (sizeof(T) == 4) {
        return *(const float4*)p;
    } else {
        half4 v = *(const half4*)p;
        return make_float4((float)v.x, (float)v.y, (float)v.z, (float)v.w);
    }
}
template<typename T>
__device__ __forceinline__ void store4(T* p, float4 v) {
    if constexpr (sizeof(T) == 4) {
        *(float4*)p = v;
    } else {
        half4 h = {(_Float16)v.x, (_Float16)v.y, (_Float16)v.z, (_Float16)v.w};
        *(half4*)p = h;
    }
}

// ---------------- CSR build ----------------

__global__ __launch_bounds__(BS) void k_zero2(int* a, int* b, int n) {
    int i = blockIdx.x * BS + threadIdx.x;
    if (i < n) { a[i] = 0; b[i] = 0; }
}

// XCD-sliced histogram: block handles dst-slice (blockIdx.x & 7) so atomics
// stay within a ~50KB cnt range (one XCD's L2 under round-robin dispatch).
__global__ __launch_bounds__(BS) void k_hist(const int* __restrict__ dst, int* __restrict__ cnt,
                                             int E, int N) {
    int slice = blockIdx.x & 7;
    int chunk = blockIdx.x >> 3;
    int lo = (int)((long long)N * slice / 8);
    int hi = (int)((long long)N * (slice + 1) / 8);
    int e0 = chunk * (BS * 4) + threadIdx.x;
    #pragma unroll
    for (int j = 0; j < 4; ++j) {
        int e = e0 + j * BS;
        if (e < E) {
            int d = dst[e];
            if (d >= lo && d < hi) atomicAdd(&cnt[d], 1);
        }
    }
}

__global__ __launch_bounds__(BS) void k_dinv(const int* __restrict__ cnt, float* __restrict__ dinv, int N) {
    int i = blockIdx.x * BS + threadIdx.x;
    if (i < N) dinv[i] = rsqrtf((float)(cnt[i] + 1));   // +1 = self-loop
}

__global__ __launch_bounds__(BS) void k_scan1(const int* __restrict__ cnt, int* __restrict__ bsum, int N) {
    __shared__ int s[BS];
    int i = blockIdx.x * BS + threadIdx.x;
    s[threadIdx.x] = (i < N) ? cnt[i] : 0;
    __syncthreads();
    for (int off = BS / 2; off > 0; off >>= 1) {
        if (threadIdx.x < off) s[threadIdx.x] += s[threadIdx.x + off];
        __syncthreads();
    }
    if (threadIdx.x == 0) bsum[blockIdx.x] = s[0];
}

__global__ __launch_bounds__(512) void k_scan2(int* bsum, int nb) {
    __shared__ int s[512];
    int t = threadIdx.x;
    int v = (t < nb) ? bsum[t] : 0;
    s[t] = v;
    __syncthreads();
    for (int off = 1; off < 512; off <<= 1) {
        int u = (t >= off) ? s[t - off] : 0;
        __syncthreads();
        s[t] += u;
        __syncthreads();
    }
    if (t < nb) bsum[t] = s[t] - v;   // exclusive of self
}

__global__ __launch_bounds__(BS) void k_scan3(const int* __restrict__ cnt, const int* __restrict__ boff,
                                              int* __restrict__ row_ptr, int N) {
    __shared__ int s[BS];
    int t = threadIdx.x;
    int i = blockIdx.x * BS + t;
    int v = (i < N) ? cnt[i] : 0;
    s[t] = v;
    __syncthreads();
    for (int off = 1; off < BS; off <<= 1) {
        int u = (t >= off) ? s[t - off] : 0;
        __syncthreads();
        s[t] += u;
        __syncthreads();
    }
    int base = boff[blockIdx.x];
    if (i < N) row_ptr[i] = base + s[t] - v;
    if (i == N - 1) row_ptr[N] = base + s[t];
}

// XCD-sliced CSR fill: block (slice, chunk) writes only edges whose dst lies
// in its N/8 slice -> per-slice entry region ~1.6MB fits one XCD L2.
__global__ __launch_bounds__(BS) void k_fill(const int* __restrict__ src, const int* __restrict__ dst,
                                             const int* __restrict__ row_ptr, int* __restrict__ fillpos,
                                             const float* __restrict__ dinv, uint2* __restrict__ entries,
                                             int E, int N) {
    int slice = blockIdx.x & 7;
    int chunk = blockIdx.x >> 3;
    int lo = (int)((long long)N * slice / 8);
    int hi = (int)((long long)N * (slice + 1) / 8);
    int e0 = chunk * (BS * 4) + threadIdx.x;
    #pragma unroll
    for (int j = 0; j < 4; ++j) {
        int e = e0 + j * BS;
        if (e < E) {
            int d = dst[e];
            if (d >= lo && d < hi) {
                int s = src[e];
                int pos = row_ptr[d] + atomicAdd(&fillpos[d], 1);
                float w = dinv[s] * dinv[d];
                entries[pos] = make_uint2((unsigned)s, __float_as_uint(w));
            }
        }
    }
}

// ---------------- dense transform ----------------
// out[N, LDOUT(pad0)] = H[N, LDIN] @ W[K, M] (+bias)(+relu).
// Single pass: thread owns one row, full M accumulators. W staged in LDS
// (padded to M4) and read via same-address float4 broadcast (conflict-free).
template<int K, int M, int LDIN, int LDOUT, bool BIAS, bool RELU, typename TOUT>
__global__ __launch_bounds__(BS) void k_gemm(const float* __restrict__ H, const float* __restrict__ Wg,
                                             const float* __restrict__ bias, TOUT* __restrict__ out, int N) {
    constexpr int M4 = (M + 3) & ~3;
    __shared__ float Wl[K * M4];
    for (int idx = threadIdx.x; idx < K * M4; idx += BS) {
        int k = idx / M4, m = idx - k * M4;
        Wl[idx] = (m < M) ? Wg[(size_t)k * M + m] : 0.f;
    }
    __syncthreads();

    int row = blockIdx.x * BS + threadIdx.x;
    bool ok = row < N;
    int rr = ok ? row : (N - 1);            // clamp: safe loads, masked stores
    const float* hp = H + (size_t)rr * LDIN;

    float acc[M4];
    #pragma unroll
    for (int m = 0; m < M4; ++m) acc[m] = 0.f;

    constexpr int K4 = K & ~3;
    #pragma unroll 2
    for (int k = 0; k < K4; k += 4) {
        float4 hv = *(const float4*)(hp + k);
        const float h[4] = {hv.x, hv.y, hv.z, hv.w};
        #pragma unroll
        for (int j = 0; j < 4; ++j) {
            const float* wl = &Wl[(k + j) * M4];
            #pragma unroll
            for (int m = 0; m < M4; m += 4) {
                float4 w = *(const float4*)(wl + m);   // ds_read_b128 broadcast
                acc[m + 0] = fmaf(h[j], w.x, acc[m + 0]);
                acc[m + 1] = fmaf(h[j], w.y, acc[m + 1]);
                acc[m + 2] = fmaf(h[j], w.z, acc[m + 2]);
                acc[m + 3] = fmaf(h[j], w.w, acc[m + 3]);
            }
        }
    }
    #pragma unroll
    for (int k = K4; k < K; ++k) {
        float h = hp[k];
        const float* wl = &Wl[k * M4];
        #pragma unroll
        for (int m = 0; m < M4; m += 4) {
            float4 w = *(const float4*)(wl + m);
            acc[m + 0] = fmaf(h, w.x, acc[m + 0]);
            acc[m + 1] = fmaf(h, w.y, acc[m + 1]);
            acc[m + 2] = fmaf(h, w.z, acc[m + 2]);
            acc[m + 3] = fmaf(h, w.w, acc[m + 3]);
        }
    }

    if (!ok) return;
    TOUT* op = out + (size_t)row * LDOUT;
    #pragma unroll
    for (int g = 0; g < LDOUT / 4; ++g) {
        int cb = 4 * g;
        float4 v;
        float* vp = &v.x;
        #pragma unroll
        for (int j = 0; j < 4; ++j) {
            int c = cb + j;
            float x = (c < M) ? acc[c] : 0.f;
            if (BIAS && c < M) x += bias[c];
            if (RELU) x = fmaxf(x, 0.f);
            vp[j] = x;
        }
        store4(op + cb, v);
    }
}

// ---------------- normalized aggregation ----------------
// out[i,:] = dinv_i^2*T[i,:] + sum_e w_e * T[src_e,:]  (+bias)(+relu)
template<typename TIN, typename TOUT, int M, int M4, bool BIAS, bool RELU>
__global__ __launch_bounds__(BS) void k_agg(const TIN* __restrict__ T, TOUT* __restrict__ out,
                                            const int* __restrict__ row_ptr, const uint2* __restrict__ entries,
                                            const float* __restrict__ dinv, const float* __restrict__ bias,
                                            int N) {
    constexpr int CG = M4 / 4;
    int idx = blockIdx.x * BS + threadIdx.x;
    if (idx >= N * CG) return;
    int i  = idx / CG;                // const divisor -> magic mul
    int cg = idx - i * CG;
    int c0 = cg * 4;

    float di = dinv[i];
    float4 t0 = load4(T + (size_t)i * M4 + c0);
    float w0 = di * di;
    float4 acc0 = make_float4(w0 * t0.x, w0 * t0.y, w0 * t0.z, w0 * t0.w);
    float4 acc1 = make_float4(0.f, 0.f, 0.f, 0.f);

    int e0 = row_ptr[i], e1 = row_ptr[i + 1];
    int e = e0;
    for (; e + 3 < e1; e += 4) {
        uint2 ea = entries[e];
        uint2 eb = entries[e + 1];
        uint2 ec = entries[e + 2];
        uint2 ed = entries[e + 3];
        float4 ta = load4(T + (size_t)ea.x * M4 + c0);
        float4 tb = load4(T + (size_t)eb.x * M4 + c0);
        float4 tc = load4(T + (size_t)ec.x * M4 + c0);
        float4 td = load4(T + (size_t)ed.x * M4 + c0);
        float wa = __uint_as_float(ea.y), wb = __uint_as_float(eb.y);
        float wc = __uint_as_float(ec.y), wd = __uint_as_float(ed.y);
        acc0.x = fmaf(wa, ta.x, acc0.x); acc0.y = fmaf(wa, ta.y, acc0.y);
        acc0.z = fmaf(wa, ta.z, acc0.z); acc0.w = fmaf(wa, ta.w, acc0.w);
        acc1.x = fmaf(wb, tb.x, acc1.x); acc1.y = fmaf(wb, tb.y, acc1.y);
        acc1.z = fmaf(wb, tb.z, acc1.z); acc1.w = fmaf(wb, tb.w, acc1.w);
        acc0.x = fmaf(wc, tc.x, acc0.x); acc0.y = fmaf(wc, tc.y, acc0.y);
        acc0.z = fmaf(wc, tc.z, acc0.z); acc0.w = fmaf(wc, tc.w, acc0.w);
        acc1.x = fmaf(wd, td.x, acc1.x); acc1.y = fmaf(wd, td.y, acc1.y);
        acc1.z = fmaf(wd, td.z, acc1.z); acc1.w = fmaf(wd, td.w, acc1.w);
    }
    for (; e < e1; ++e) {
        uint2 ea = entries[e];
        float4 ta = load4(T + (size_t)ea.x * M4 + c0);
        float wa = __uint_as_float(ea.y);
        acc0.x = fmaf(wa, ta.x, acc0.x); acc0.y = fmaf(wa, ta.y, acc0.y);
        acc0.z = fmaf(wa, ta.z, acc0.z); acc0.w = fmaf(wa, ta.w, acc0.w);
    }
    acc0.x += acc1.x; acc0.y += acc1.y; acc0.z += acc1.z; acc0.w += acc1.w;

    float* vp = &acc0.x;
    #pragma unroll
    for (int j = 0; j < 4; ++j) {
        if (BIAS && (c0 + j) < M) vp[j] += bias[c0 + j];
        if (RELU) vp[j] = fmaxf(vp[j], 0.f);
    }
    store4(out + (size_t)i * M4 + c0, acc0);
}

// ---------------- driver ----------------

extern "C" void kernel_launch(void* const* d_in, const int* in_sizes, int n_in,
                              void* d_out, int out_size, void* d_ws, size_t ws_size,
                              hipStream_t stream) {
    const float* x  = (const float*)d_in[0];
    const float* W1 = (const float*)d_in[1];
    const float* b1 = (const float*)d_in[2];
    const float* W2 = (const float*)d_in[3];
    const float* b2 = (const float*)d_in[4];
    const float* W3 = (const float*)d_in[5];
    const float* b3 = (const float*)d_in[6];
    const float* W4 = (const float*)d_in[7];
    const float* b4 = (const float*)d_in[8];
    const int* edge_index = (const int*)d_in[9];

    const int N = in_sizes[0] / 88;
    const int E = in_sizes[9] / 2;
    const int* src = edge_index;
    const int* dst = edge_index + E;

    char* p = (char*)d_ws;
    auto carve = [&](size_t bytes) { void* r = p; p += (bytes + 255) & ~(size_t)255; return r; };
    int*   cnt     = (int*)  carve((size_t)N * 4);
    float* dinv    = (float*)carve((size_t)N * 4);
    int*   row_ptr = (int*)  carve((size_t)(N + 1) * 4);
    int*   fillpos = (int*)  carve((size_t)N * 4);
    int*   bsum    = (int*)  carve(4096);
    uint2* entries = (uint2*)carve((size_t)E * 8);
    _Float16* hA   = (_Float16*)carve((size_t)N * 68 * 2);
    _Float16* hB   = (_Float16*)carve((size_t)N * 68 * 2);
    float*    fA   = (float*)   carve((size_t)N * 68 * 4);

    int gN = (N + BS - 1) / BS;
    int chunks = (E + BS * 4 - 1) / (BS * 4);

    k_zero2<<<gN, BS, 0, stream>>>(cnt, fillpos, N);
    k_hist <<<chunks * 8, BS, 0, stream>>>(dst, cnt, E, N);
    k_dinv <<<gN, BS, 0, stream>>>(cnt, dinv, N);
    int nb = gN;
    k_scan1<<<nb, BS, 0, stream>>>(cnt, bsum, N);
    k_scan2<<<1, 512, 0, stream>>>(bsum, nb);
    k_scan3<<<nb, BS, 0, stream>>>(cnt, bsum, row_ptr, N);
    k_fill <<<chunks * 8, BS, 0, stream>>>(src, dst, row_ptr, fillpos, dinv, entries, E, N);

    auto agg_grid = [&](int CG) { return (N * CG + BS - 1) / BS; };

    // G1: x(f32,88) @ W1 -> hA(half,68)
    k_gemm<88, 65, 88, 68, false, false, _Float16><<<gN, BS, 0, stream>>>(x, W1, nullptr, hA, N);
    // A1: agg(hA) +b1 +relu -> fA(f32,68)
    k_agg<_Float16, float, 65, 68, true, true><<<agg_grid(17), BS, 0, stream>>>(hA, fA, row_ptr, entries, dinv, b1, N);
    // G2: fA(68) @ W2 -> hB(half,52)
    k_gemm<65, 50, 68, 52, false, false, _Float16><<<gN, BS, 0, stream>>>(fA, W2, nullptr, hB, N);
    // A2: agg(hB) +b2 -> hA(half,52)
    k_agg<_Float16, _Float16, 50, 52, true, false><<<agg_grid(13), BS, 0, stream>>>(hB, hA, row_ptr, entries, dinv, b2, N);
    // A3: agg(hA) -> fA(f32,52)
    k_agg<_Float16, float, 50, 52, false, false><<<agg_grid(13), BS, 0, stream>>>(hA, fA, row_ptr, entries, dinv, nullptr, N);
    // G3: fA(52) @ W3 +b3 +relu -> hB(half,68)
    k_gemm<50, 65, 52, 68, true, true, _Float16><<<gN, BS, 0, stream>>>(fA, W3, b3, hB, N);
    // A4: agg(hB) -> fA(f32,68)
    k_agg<_Float16, float, 65, 68, false, false><<<agg_grid(17), BS, 0, stream>>>(hB, fA, row_ptr, entries, dinv, nullptr, N);
    // G4: fA(68) @ W4 +b4 -> d_out(f32,88)
    k_gemm<65, 88, 68, 88, true, false, float><<<gN, BS, 0, stream>>>(fA, W4, b4, (float*)d_out, N);
}